// Round 2
// baseline (510.127 us; speedup 1.0000x reference)
//
#include <hip/hip_runtime.h>
#include <hip/hip_bf16.h>

typedef float f32x4 __attribute__((ext_vector_type(4)));
typedef __bf16 bf16x8 __attribute__((ext_vector_type(8)));

#define NPOS 361
#define NBATCH 128
#define M_TOT (NBATCH * NPOS)   // 46208

// ---------------- kernel 0: transpose weights to (N x K) bf16 ----------------
__global__ __launch_bounds__(256) void prep_w_kernel(
    const float* __restrict__ qw, const float* __restrict__ kw,
    const float* __restrict__ vw, const float* __restrict__ ow,
    __hip_bfloat16* __restrict__ wqkvt, __hip_bfloat16* __restrict__ owt) {
  int idx = blockIdx.x * 256 + threadIdx.x;
  const int TOT1 = 1152 * 384;
  if (idx < TOT1) {
    int n = idx / 384, kk = idx % 384;
    const float* src = (n < 384) ? qw : (n < 768 ? kw : vw);
    int nn = n % 384;
    wqkvt[idx] = __float2bfloat16(src[kk * 384 + nn]);
  } else if (idx < TOT1 + 384 * 384) {
    int j = idx - TOT1;
    int n = j / 384, kk = j % 384;
    owt[j] = __float2bfloat16(ow[kk * 384 + n]);
  }
}

// ---------------- kernel 1: transpose (B,C,N)->(B,N,C) + RMSNorm -> bf16 ----
__global__ __launch_bounds__(256) void rms_t_kernel(
    const float* __restrict__ x, const float* __restrict__ nw,
    __hip_bfloat16* __restrict__ xn) {
  int b = blockIdx.x / 12, nt = blockIdx.x % 12;
  int n0 = nt * 32;
  __shared__ float xt[384][33];  // +1 pad: conflict-free column reads
  int tid = threadIdx.x;
  const float* xb = x + (size_t)b * (384 * 361);
  for (int idx = tid; idx < 384 * 32; idx += 256) {
    int c = idx >> 5, j = idx & 31;
    float v = 0.f;
    int n = n0 + j;
    if (n < 361) v = xb[c * 361 + n];
    xt[c][j] = v;
  }
  __syncthreads();
  int lane = tid & 63, wid = tid >> 6;
  for (int j = wid; j < 32; j += 4) {
    int n = n0 + j;
    if (n >= 361) break;
    float vals[6];
    float ss = 0.f;
#pragma unroll
    for (int i = 0; i < 6; ++i) { vals[i] = xt[lane + i * 64][j]; ss += vals[i] * vals[i]; }
#pragma unroll
    for (int off = 1; off < 64; off <<= 1) ss += __shfl_xor(ss, off);
    float inv = rsqrtf(ss * (1.f / 384.f) + 1e-6f);
    size_t row = (size_t)b * 361 + n;
#pragma unroll
    for (int i = 0; i < 6; ++i) {
      int c = lane + i * 64;
      xn[row * 384 + c] = __float2bfloat16(vals[i] * inv * nw[c]);
    }
  }
}

// ---------------- kernel 2: QKV GEMM (M=46208, N=1152, K=384), bf16 MFMA ----
__global__ __launch_bounds__(256) void qkv_gemm_kernel(
    const __hip_bfloat16* __restrict__ A, const __hip_bfloat16* __restrict__ BT,
    __hip_bfloat16* __restrict__ qkv) {
  const int m0 = blockIdx.x * 128;
  const int n0 = blockIdx.y * 128;
  __shared__ __hip_bfloat16 As[128][40];  // stride 40 bf16 = 80B -> 2-way max
  __shared__ __hip_bfloat16 Bs[128][40];
  const int tid = threadIdx.x;
  const int lane = tid & 63, wid = tid >> 6;
  const int wr = wid >> 1, wc = wid & 1;
  const int cB = lane & 15, koff = (lane >> 4) * 8;
  f32x4 acc[4][4] = {};
  for (int k0 = 0; k0 < 384; k0 += 32) {
    __syncthreads();
    {
      int row = tid >> 2, c8 = (tid & 3) * 8;
      *reinterpret_cast<bf16x8*>(&As[row][c8]) =
          *reinterpret_cast<const bf16x8*>(&A[(size_t)(m0 + row) * 384 + k0 + c8]);
      *reinterpret_cast<bf16x8*>(&Bs[row][c8]) =
          *reinterpret_cast<const bf16x8*>(&BT[(size_t)(n0 + row) * 384 + k0 + c8]);
      row += 64;
      *reinterpret_cast<bf16x8*>(&As[row][c8]) =
          *reinterpret_cast<const bf16x8*>(&A[(size_t)(m0 + row) * 384 + k0 + c8]);
      *reinterpret_cast<bf16x8*>(&Bs[row][c8]) =
          *reinterpret_cast<const bf16x8*>(&BT[(size_t)(n0 + row) * 384 + k0 + c8]);
    }
    __syncthreads();
    bf16x8 af[4], bfr[4];
#pragma unroll
    for (int i = 0; i < 4; ++i)
      af[i] = *reinterpret_cast<const bf16x8*>(&As[wr * 64 + i * 16 + cB][koff]);
#pragma unroll
    for (int j = 0; j < 4; ++j)
      bfr[j] = *reinterpret_cast<const bf16x8*>(&Bs[wc * 64 + j * 16 + cB][koff]);
#pragma unroll
    for (int i = 0; i < 4; ++i)
#pragma unroll
      for (int j = 0; j < 4; ++j)
        acc[i][j] = __builtin_amdgcn_mfma_f32_16x16x32_bf16(af[i], bfr[j], acc[i][j], 0, 0, 0);
  }
  const int rg = lane >> 4;
  const int sel = n0 / 384;  // uniform per block (128 | 384 boundaries align)
  __hip_bfloat16* dst = qkv + (size_t)sel * M_TOT * 384;
#pragma unroll
  for (int i = 0; i < 4; ++i)
#pragma unroll
    for (int j = 0; j < 4; ++j) {
      int cc = n0 - sel * 384 + wc * 64 + j * 16 + cB;
#pragma unroll
      for (int r = 0; r < 4; ++r) {
        int row = m0 + wr * 64 + i * 16 + rg * 4 + r;
        dst[(size_t)row * 384 + cc] = __float2bfloat16(acc[i][j][r]);
      }
    }
}

// ---------------- kernel 3: RoPE in-place on q,k (first 2*M_TOT rows) -------
__global__ __launch_bounds__(256) void rope_kernel(
    __hip_bfloat16* __restrict__ qk, const float* __restrict__ cost,
    const float* __restrict__ sint) {
  size_t idx = (size_t)blockIdx.x * 256 + threadIdx.x;
  const size_t TOT = (size_t)2 * M_TOT * 192;
  if (idx >= TOT) return;
  int p = (int)(idx % 192);
  size_t row = idx / 192;
  int n = (int)(row % 361);  // 46208 = 128*361, so row%361 == position
  int dp = p & 15, h = p >> 4;
  __hip_bfloat16* ptr = qk + row * 384 + h * 32 + dp * 2;
  float x0 = __bfloat162float(ptr[0]);
  float x1 = __bfloat162float(ptr[1]);
  int ci = n * 32 + dp * 2;
  float c0 = cost[ci], s0 = sint[ci];
  float c1 = cost[ci + 1], s1 = sint[ci + 1];
  ptr[0] = __float2bfloat16(x0 * c0 - x1 * s0);
  ptr[1] = __float2bfloat16(x1 * c1 + x0 * s1);
}

// ---------------- kernel 4: attention, one (b,h) per block, 8 waves --------
__global__ __launch_bounds__(512) void attn_kernel(
    const __hip_bfloat16* __restrict__ q, const __hip_bfloat16* __restrict__ k,
    const __hip_bfloat16* __restrict__ v, __hip_bfloat16* __restrict__ o) {
  const int b = blockIdx.x / 12, h = blockIdx.x % 12;
  __shared__ __hip_bfloat16 Ks[368][40];   // K rows, 2-way max on b-frag reads
  __shared__ __hip_bfloat16 VT[32][392];   // V transposed; cols >=361 zeroed
  __shared__ __hip_bfloat16 Pb[8][16][40]; // per-wave P chunk (16x32)
  const int tid = threadIdx.x, lane = tid & 63, wid = tid >> 6;
  const size_t base = ((size_t)b * 361) * 384 + (size_t)h * 32;
  const __hip_bfloat16* qb = q + base;
  const __hip_bfloat16* kb = k + base;
  const __hip_bfloat16* vb = v + base;
  for (int idx = tid; idx < 368 * 4; idx += 512) {
    int m = idx >> 2, c8 = (idx & 3) * 8;
    int mc = m < 361 ? m : 360;  // rows >=361 get masked later; just keep finite
    *reinterpret_cast<bf16x8*>(&Ks[m][c8]) =
        *reinterpret_cast<const bf16x8*>(&kb[(size_t)mc * 384 + c8]);
  }
  for (int idx = tid; idx < 384 * 32; idx += 512) {
    int m = idx >> 5, d = idx & 31;
    float val = (m < 361) ? __bfloat162float(vb[(size_t)m * 384 + d]) : 0.f;
    VT[d][m] = __float2bfloat16(val);
  }
  __syncthreads();
  const int cB = lane & 15, rg = lane >> 4, koff = rg * 8;
  const float scale = 0.17677669529663688f;  // 1/sqrt(32)
  for (int rt = wid; rt < 23; rt += 8) {
    int qrow = rt * 16 + cB;
    if (qrow > 360) qrow = 360;  // clamped rows produce unstored garbage only
    bf16x8 af = *reinterpret_cast<const bf16x8*>(&qb[(size_t)qrow * 384 + koff]);
    f32x4 S[23];
#pragma unroll
    for (int mt = 0; mt < 23; ++mt) {
      bf16x8 bfr = *reinterpret_cast<const bf16x8*>(&Ks[mt * 16 + cB][koff]);
      f32x4 z = {};
      S[mt] = __builtin_amdgcn_mfma_f32_16x16x32_bf16(af, bfr, z, 0, 0, 0);
    }
    float mx[4] = {-1e30f, -1e30f, -1e30f, -1e30f};
#pragma unroll
    for (int mt = 0; mt < 23; ++mt)
#pragma unroll
      for (int r = 0; r < 4; ++r) {
        float s = S[mt][r] * scale;
        if (mt == 22 && cB >= 9) s = -1e30f;  // cols 361..367 masked
        S[mt][r] = s;
        mx[r] = fmaxf(mx[r], s);
      }
#pragma unroll
    for (int off = 1; off < 16; off <<= 1)
#pragma unroll
      for (int r = 0; r < 4; ++r) mx[r] = fmaxf(mx[r], __shfl_xor(mx[r], off));
    float sum[4] = {0.f, 0.f, 0.f, 0.f};
#pragma unroll
    for (int mt = 0; mt < 23; ++mt)
#pragma unroll
      for (int r = 0; r < 4; ++r) {
        float pv = __expf(S[mt][r] - mx[r]);
        S[mt][r] = pv;
        sum[r] += pv;
      }
#pragma unroll
    for (int off = 1; off < 16; off <<= 1)
#pragma unroll
      for (int r = 0; r < 4; ++r) sum[r] += __shfl_xor(sum[r], off);
    f32x4 O0 = {}, O1 = {};
#pragma unroll
    for (int km = 0; km < 12; ++km) {
#pragma unroll
      for (int t2 = 0; t2 < 2; ++t2) {
        int mt = km * 2 + t2;
#pragma unroll
        for (int r = 0; r < 4; ++r) {
          float pv = (mt < 23) ? S[mt][r] : 0.f;
          Pb[wid][rg * 4 + r][t2 * 16 + cB] = __float2bfloat16(pv);
        }
      }
      // same-wave DS ops are ordered; compiler inserts lgkmcnt for the reads
      bf16x8 pa = *reinterpret_cast<const bf16x8*>(&Pb[wid][cB][koff]);
      bf16x8 bv0 = *reinterpret_cast<const bf16x8*>(&VT[cB][km * 32 + koff]);
      bf16x8 bv1 = *reinterpret_cast<const bf16x8*>(&VT[16 + cB][km * 32 + koff]);
      O0 = __builtin_amdgcn_mfma_f32_16x16x32_bf16(pa, bv0, O0, 0, 0, 0);
      O1 = __builtin_amdgcn_mfma_f32_16x16x32_bf16(pa, bv1, O1, 0, 0, 0);
    }
#pragma unroll
    for (int r = 0; r < 4; ++r) {
      int n = rt * 16 + rg * 4 + r;
      if (n < 361) {
        float is = 1.f / sum[r];
        o[base + (size_t)n * 384 + cB] = __float2bfloat16(O0[r] * is);
        o[base + (size_t)n * 384 + 16 + cB] = __float2bfloat16(O1[r] * is);
      }
    }
  }
}

// ---------------- kernel 5: out-proj GEMM + residual (f32 out) -------------
__global__ __launch_bounds__(256) void out_gemm_kernel(
    const __hip_bfloat16* __restrict__ A, const __hip_bfloat16* __restrict__ BT,
    const float* __restrict__ x, float* __restrict__ out) {
  const int m0 = blockIdx.x * 128;
  const int n0 = blockIdx.y * 128;
  __shared__ __hip_bfloat16 As[128][40];
  __shared__ __hip_bfloat16 Bs[128][40];
  const int tid = threadIdx.x;
  const int lane = tid & 63, wid = tid >> 6;
  const int wr = wid >> 1, wc = wid & 1;
  const int cB = lane & 15, koff = (lane >> 4) * 8;
  f32x4 acc[4][4] = {};
  for (int k0 = 0; k0 < 384; k0 += 32) {
    __syncthreads();
    {
      int row = tid >> 2, c8 = (tid & 3) * 8;
      *reinterpret_cast<bf16x8*>(&As[row][c8]) =
          *reinterpret_cast<const bf16x8*>(&A[(size_t)(m0 + row) * 384 + k0 + c8]);
      *reinterpret_cast<bf16x8*>(&Bs[row][c8]) =
          *reinterpret_cast<const bf16x8*>(&BT[(size_t)(n0 + row) * 384 + k0 + c8]);
      row += 64;
      *reinterpret_cast<bf16x8*>(&As[row][c8]) =
          *reinterpret_cast<const bf16x8*>(&A[(size_t)(m0 + row) * 384 + k0 + c8]);
      *reinterpret_cast<bf16x8*>(&Bs[row][c8]) =
          *reinterpret_cast<const bf16x8*>(&BT[(size_t)(n0 + row) * 384 + k0 + c8]);
    }
    __syncthreads();
    bf16x8 af[4], bfr[4];
#pragma unroll
    for (int i = 0; i < 4; ++i)
      af[i] = *reinterpret_cast<const bf16x8*>(&As[wr * 64 + i * 16 + cB][koff]);
#pragma unroll
    for (int j = 0; j < 4; ++j)
      bfr[j] = *reinterpret_cast<const bf16x8*>(&Bs[wc * 64 + j * 16 + cB][koff]);
#pragma unroll
    for (int i = 0; i < 4; ++i)
#pragma unroll
      for (int j = 0; j < 4; ++j)
        acc[i][j] = __builtin_amdgcn_mfma_f32_16x16x32_bf16(af[i], bfr[j], acc[i][j], 0, 0, 0);
  }
  const int rg = lane >> 4;
#pragma unroll
  for (int i = 0; i < 4; ++i)
#pragma unroll
    for (int j = 0; j < 4; ++j) {
      int col = n0 + wc * 64 + j * 16 + cB;
#pragma unroll
      for (int r = 0; r < 4; ++r) {
        int row = m0 + wr * 64 + i * 16 + rg * 4 + r;
        int bb = row / 361;
        int n = row - bb * 361;
        float res = x[((size_t)bb * 384 + col) * 361 + n];
        out[(size_t)row * 384 + col] = acc[i][j][r] + res;
      }
    }
}

extern "C" void kernel_launch(void* const* d_in, const int* in_sizes, int n_in,
                              void* d_out, int out_size, void* d_ws, size_t ws_size,
                              hipStream_t stream) {
  const float* x    = (const float*)d_in[0];
  const float* qw   = (const float*)d_in[1];
  const float* kw   = (const float*)d_in[2];
  const float* vw   = (const float*)d_in[3];
  const float* ow   = (const float*)d_in[4];
  const float* nw   = (const float*)d_in[5];
  const float* cost = (const float*)d_in[6];
  const float* sint = (const float*)d_in[7];
  float* out = (float*)d_out;
  char* ws = (char*)d_ws;

  const size_t SZ_XN = (size_t)M_TOT * 384 * 2;  // 35,487,744
  __hip_bfloat16* xn    = (__hip_bfloat16*)(ws);
  __hip_bfloat16* qkv   = (__hip_bfloat16*)(ws + SZ_XN);
  __hip_bfloat16* wqkvt = (__hip_bfloat16*)(ws + SZ_XN * 4);
  __hip_bfloat16* owt   = (__hip_bfloat16*)(ws + SZ_XN * 4 + 1152 * 384 * 2);
  __hip_bfloat16* ao    = xn;  // xn is dead after QKV GEMM; reuse for attn out

  prep_w_kernel<<<2304, 256, 0, stream>>>(qw, kw, vw, ow, wqkvt, owt);
  rms_t_kernel<<<128 * 12, 256, 0, stream>>>(x, nw, xn);
  qkv_gemm_kernel<<<dim3(361, 9), 256, 0, stream>>>(xn, wqkvt, qkv);
  {
    size_t tot = (size_t)2 * M_TOT * 192;
    int blocks = (int)((tot + 255) / 256);
    rope_kernel<<<blocks, 256, 0, stream>>>(qkv, cost, sint);
  }
  attn_kernel<<<128 * 12, 512, 0, stream>>>(qkv, qkv + (size_t)M_TOT * 384,
                                            qkv + (size_t)2 * M_TOT * 384, ao);
  out_gemm_kernel<<<dim3(361, 3), 256, 0, stream>>>(ao, owt, x, out);
}

// Round 8
// 467.479 us; speedup vs baseline: 1.0912x; 1.0912x over previous
//
#include <hip/hip_runtime.h>
#include <hip/hip_bf16.h>

typedef float f32x4 __attribute__((ext_vector_type(4)));
typedef __bf16 bf16x8 __attribute__((ext_vector_type(8)));

#define NPOS 361
#define NBATCH 128
#define M_TOT (NBATCH * NPOS)   // 46208

__device__ inline void gload16(const void* g, void* l) {
  __builtin_amdgcn_global_load_lds(
      (const __attribute__((address_space(1))) void*)g,
      (__attribute__((address_space(3))) void*)l, 16, 0, 0);
}

// ---------------- kernel 0: LDS-tiled transpose of weights -> (N x K) bf16 ---
__global__ __launch_bounds__(256) void prep_w_kernel(
    const float* __restrict__ qw, const float* __restrict__ kw,
    const float* __restrict__ vw, const float* __restrict__ ow,
    __hip_bfloat16* __restrict__ wqkvt, __hip_bfloat16* __restrict__ owt) {
  int bid = blockIdx.x;                 // 4 * 144
  int si = bid / 144, t = bid % 144;
  int tr = (t / 12) * 32, tc = (t % 12) * 32;
  const float* src = si == 0 ? qw : si == 1 ? kw : si == 2 ? vw : ow;
  __hip_bfloat16* dst = si < 3 ? wqkvt + si * 147456 : owt;
  __shared__ float tile[32][33];
  int c = threadIdx.x & 31, r0 = threadIdx.x >> 5;
#pragma unroll
  for (int i = 0; i < 4; ++i) {
    int r = r0 + i * 8;
    tile[r][c] = src[(size_t)(tr + r) * 384 + tc + c];  // coalesced read
  }
  __syncthreads();
#pragma unroll
  for (int i = 0; i < 4; ++i) {
    int r = r0 + i * 8;
    dst[(size_t)(tc + r) * 384 + tr + c] = __float2bfloat16(tile[c][r]);  // coalesced write
  }
}

// ---------------- kernel 1: transpose (B,C,N)->(B,N,C) + RMSNorm -> bf16 ----
__global__ __launch_bounds__(256) void rms_t_kernel(
    const float* __restrict__ x, const float* __restrict__ nw,
    __hip_bfloat16* __restrict__ xn) {
  int b = blockIdx.x / 12, nt = blockIdx.x % 12;
  int n0 = nt * 32;
  __shared__ float xt[32 * 388];  // row len 388: 16B-aligned rows
  int tid = threadIdx.x;
  const float* xb = x + (size_t)b * (384 * 361);
  for (int idx = tid; idx < 384 * 32; idx += 256) {
    int j = idx & 31, c = idx >> 5;
    int n = n0 + j;
    xt[j * 388 + c] = (n < 361) ? xb[c * 361 + n] : 0.f;  // coalesced in n
  }
  __syncthreads();
  int lane = tid & 63, wid = tid >> 6;
  for (int j = wid; j < 32; j += 4) {
    int n = n0 + j;
    if (n >= 361) break;
    const float* row = &xt[j * 388];
    f32x4 v4 = *(const f32x4*)&row[lane * 4];         // c = 4*lane .. +3
    float va = row[256 + 2 * lane], vb2 = row[256 + 2 * lane + 1];
    float ss = v4[0] * v4[0] + v4[1] * v4[1] + v4[2] * v4[2] + v4[3] * v4[3] +
               va * va + vb2 * vb2;
#pragma unroll
    for (int off = 1; off < 64; off <<= 1) ss += __shfl_xor(ss, off);
    float inv = rsqrtf(ss * (1.f / 384.f) + 1e-6f);
    f32x4 w4 = *(const f32x4*)&nw[lane * 4];
    float wa = nw[256 + 2 * lane], wb = nw[256 + 2 * lane + 1];
    size_t rowo = ((size_t)b * 361 + n) * 384;
    __hip_bfloat162 p0 = __float22bfloat162_rn({v4[0] * inv * w4[0], v4[1] * inv * w4[1]});
    __hip_bfloat162 p1 = __float22bfloat162_rn({v4[2] * inv * w4[2], v4[3] * inv * w4[3]});
    __hip_bfloat162 p2 = __float22bfloat162_rn({va * inv * wa, vb2 * inv * wb});
    *(__hip_bfloat162*)&xn[rowo + lane * 4] = p0;
    *(__hip_bfloat162*)&xn[rowo + lane * 4 + 2] = p1;
    *(__hip_bfloat162*)&xn[rowo + 256 + 2 * lane] = p2;
  }
}

// ---------------- kernel 2: QKV GEMM, m97-style global_load_lds staging -----
__global__ __launch_bounds__(256) void qkv_gemm_kernel(
    const __hip_bfloat16* __restrict__ A, const __hip_bfloat16* __restrict__ BT,
    __hip_bfloat16* __restrict__ qkv) {
  const int nwg = 361 * 9;
  int orig = blockIdx.x;
  int xcd = orig & 7, loc = orig >> 3;
  const int q8 = nwg >> 3, r8 = nwg & 7;  // 406, 1 — bijective XCD swizzle (m204)
  int wgid = (xcd < r8 ? xcd * (q8 + 1) : r8 * (q8 + 1) + (xcd - r8) * q8) + loc;
  const int mt = wgid / 9, nt = wgid % 9;
  const int m0 = mt * 128, n0 = nt * 128;
  __shared__ __hip_bfloat16 As[128 * 32];  // linear: required by global_load_lds
  __shared__ __hip_bfloat16 Bs[128 * 32];
  const int tid = threadIdx.x, lane = tid & 63, wid = tid >> 6;
  const int wr = wid >> 1, wc = wid & 1;
  const int cB = lane & 15, koff = (lane >> 4) * 8;
  const int rS0 = wid * 32 + (lane >> 2);       // staging row, issue 0
  const int rS1 = rS0 + 16;                     // issue 1
  const int cby = (lane & 3) * 16;              // byte offset within 64B LDS row
  f32x4 acc[4][4] = {};
  for (int k0 = 0; k0 < 384; k0 += 32) {
    __syncthreads();
    gload16((const char*)(A + (size_t)(m0 + rS0) * 384 + k0) + cby, As + wid * 1024);
    gload16((const char*)(A + (size_t)(m0 + rS1) * 384 + k0) + cby, As + wid * 1024 + 512);
    gload16((const char*)(BT + (size_t)(n0 + rS0) * 384 + k0) + cby, Bs + wid * 1024);
    gload16((const char*)(BT + (size_t)(n0 + rS1) * 384 + k0) + cby, Bs + wid * 1024 + 512);
    __syncthreads();  // compiler drains vmcnt before barrier
    bf16x8 af[4], bfr[4];
#pragma unroll
    for (int i = 0; i < 4; ++i)
      af[i] = *reinterpret_cast<const bf16x8*>(&As[(wr * 64 + i * 16 + cB) * 32 + koff]);
#pragma unroll
    for (int j = 0; j < 4; ++j)
      bfr[j] = *reinterpret_cast<const bf16x8*>(&Bs[(wc * 64 + j * 16 + cB) * 32 + koff]);
#pragma unroll
    for (int i = 0; i < 4; ++i)
#pragma unroll
      for (int j = 0; j < 4; ++j)
        acc[i][j] = __builtin_amdgcn_mfma_f32_16x16x32_bf16(af[i], bfr[j], acc[i][j], 0, 0, 0);
  }
  const int rg = lane >> 4;
  const int sel = n0 / 384;
  __hip_bfloat16* dst = qkv + (size_t)sel * M_TOT * 384;
#pragma unroll
  for (int i = 0; i < 4; ++i)
#pragma unroll
    for (int j = 0; j < 4; ++j) {
      int cc = n0 - sel * 384 + wc * 64 + j * 16 + cB;
#pragma unroll
      for (int r = 0; r < 4; ++r) {
        int row = m0 + wr * 64 + i * 16 + rg * 4 + r;
        dst[(size_t)row * 384 + cc] = __float2bfloat16(acc[i][j][r]);
      }
    }
}

// ---------------- kernel 3: RoPE in-place on q,k (round-2 verbatim) ---------
__global__ __launch_bounds__(256) void rope_kernel(
    __hip_bfloat16* __restrict__ qk, const float* __restrict__ cost,
    const float* __restrict__ sint) {
  size_t idx = (size_t)blockIdx.x * 256 + threadIdx.x;
  const size_t TOT = (size_t)2 * M_TOT * 192;
  if (idx >= TOT) return;
  int p = (int)(idx % 192);
  size_t row = idx / 192;
  int n = (int)(row % 361);  // 46208 = 128*361, so row%361 == position
  int dp = p & 15, h = p >> 4;
  __hip_bfloat16* ptr = qk + row * 384 + h * 32 + dp * 2;
  float x0 = __bfloat162float(ptr[0]);
  float x1 = __bfloat162float(ptr[1]);
  int ci = n * 32 + dp * 2;
  float c0 = cost[ci], s0 = sint[ci];
  float c1 = cost[ci + 1], s1 = sint[ci + 1];
  ptr[0] = __float2bfloat16(x0 * c0 - x1 * s0);
  ptr[1] = __float2bfloat16(x1 * c1 + x0 * s1);
}

// ---------------- kernel 4: attention (round-2 verbatim, passed 0.031) -----
__global__ __launch_bounds__(512) void attn_kernel(
    const __hip_bfloat16* __restrict__ q, const __hip_bfloat16* __restrict__ k,
    const __hip_bfloat16* __restrict__ v, __hip_bfloat16* __restrict__ o) {
  const int b = blockIdx.x / 12, h = blockIdx.x % 12;
  __shared__ __hip_bfloat16 Ks[368][40];   // K rows, 2-way max on b-frag reads
  __shared__ __hip_bfloat16 VT[32][392];   // V transposed; cols >=361 zeroed
  __shared__ __hip_bfloat16 Pb[8][16][40]; // per-wave P chunk (16x32)
  const int tid = threadIdx.x, lane = tid & 63, wid = tid >> 6;
  const size_t base = ((size_t)b * 361) * 384 + (size_t)h * 32;
  const __hip_bfloat16* qb = q + base;
  const __hip_bfloat16* kb = k + base;
  const __hip_bfloat16* vb = v + base;
  for (int idx = tid; idx < 368 * 4; idx += 512) {
    int m = idx >> 2, c8 = (idx & 3) * 8;
    int mc = m < 361 ? m : 360;  // rows >=361 get masked later; just keep finite
    *reinterpret_cast<bf16x8*>(&Ks[m][c8]) =
        *reinterpret_cast<const bf16x8*>(&kb[(size_t)mc * 384 + c8]);
  }
  for (int idx = tid; idx < 384 * 32; idx += 512) {
    int m = idx >> 5, d = idx & 31;
    float val = (m < 361) ? __bfloat162float(vb[(size_t)m * 384 + d]) : 0.f;
    VT[d][m] = __float2bfloat16(val);
  }
  __syncthreads();
  const int cB = lane & 15, rg = lane >> 4, koff = rg * 8;
  const float scale = 0.17677669529663688f;  // 1/sqrt(32)
  for (int rt = wid; rt < 23; rt += 8) {
    int qrow = rt * 16 + cB;
    if (qrow > 360) qrow = 360;  // clamped rows produce unstored garbage only
    bf16x8 af = *reinterpret_cast<const bf16x8*>(&qb[(size_t)qrow * 384 + koff]);
    f32x4 S[23];
#pragma unroll
    for (int mt = 0; mt < 23; ++mt) {
      bf16x8 bfr = *reinterpret_cast<const bf16x8*>(&Ks[mt * 16 + cB][koff]);
      f32x4 z = {};
      S[mt] = __builtin_amdgcn_mfma_f32_16x16x32_bf16(af, bfr, z, 0, 0, 0);
    }
    float mx[4] = {-1e30f, -1e30f, -1e30f, -1e30f};
#pragma unroll
    for (int mt = 0; mt < 23; ++mt)
#pragma unroll
      for (int r = 0; r < 4; ++r) {
        float s = S[mt][r] * scale;
        if (mt == 22 && cB >= 9) s = -1e30f;  // cols 361..367 masked
        S[mt][r] = s;
        mx[r] = fmaxf(mx[r], s);
      }
#pragma unroll
    for (int off = 1; off < 16; off <<= 1)
#pragma unroll
      for (int r = 0; r < 4; ++r) mx[r] = fmaxf(mx[r], __shfl_xor(mx[r], off));
    float sum[4] = {0.f, 0.f, 0.f, 0.f};
#pragma unroll
    for (int mt = 0; mt < 23; ++mt)
#pragma unroll
      for (int r = 0; r < 4; ++r) {
        float pv = __expf(S[mt][r] - mx[r]);
        S[mt][r] = pv;
        sum[r] += pv;
      }
#pragma unroll
    for (int off = 1; off < 16; off <<= 1)
#pragma unroll
      for (int r = 0; r < 4; ++r) sum[r] += __shfl_xor(sum[r], off);
    f32x4 O0 = {}, O1 = {};
#pragma unroll
    for (int km = 0; km < 12; ++km) {
#pragma unroll
      for (int t2 = 0; t2 < 2; ++t2) {
        int mt = km * 2 + t2;
#pragma unroll
        for (int r = 0; r < 4; ++r) {
          float pv = (mt < 23) ? S[mt][r] : 0.f;
          Pb[wid][rg * 4 + r][t2 * 16 + cB] = __float2bfloat16(pv);
        }
      }
      // same-wave DS ops are ordered; compiler inserts lgkmcnt for the reads
      bf16x8 pa = *reinterpret_cast<const bf16x8*>(&Pb[wid][cB][koff]);
      bf16x8 bv0 = *reinterpret_cast<const bf16x8*>(&VT[cB][km * 32 + koff]);
      bf16x8 bv1 = *reinterpret_cast<const bf16x8*>(&VT[16 + cB][km * 32 + koff]);
      O0 = __builtin_amdgcn_mfma_f32_16x16x32_bf16(pa, bv0, O0, 0, 0, 0);
      O1 = __builtin_amdgcn_mfma_f32_16x16x32_bf16(pa, bv1, O1, 0, 0, 0);
    }
#pragma unroll
    for (int r = 0; r < 4; ++r) {
      int n = rt * 16 + rg * 4 + r;
      if (n < 361) {
        float is = 1.f / sum[r];
        o[base + (size_t)n * 384 + cB] = __float2bfloat16(O0[r] * is);
        o[base + (size_t)n * 384 + 16 + cB] = __float2bfloat16(O1[r] * is);
      }
    }
  }
}

// ---------------- kernel 5: out-proj GEMM + residual (f32 out) --------------
__global__ __launch_bounds__(256) void out_gemm_kernel(
    const __hip_bfloat16* __restrict__ A, const __hip_bfloat16* __restrict__ BT,
    const float* __restrict__ x, float* __restrict__ out) {
  const int nwg = 361 * 3;
  int orig = blockIdx.x;
  int xcd = orig & 7, loc = orig >> 3;
  const int q8 = nwg >> 3, r8 = nwg & 7;  // 135, 3
  int wgid = (xcd < r8 ? xcd * (q8 + 1) : r8 * (q8 + 1) + (xcd - r8) * q8) + loc;
  const int mt = wgid / 3, nt = wgid % 3;
  const int m0 = mt * 128, n0 = nt * 128;
  __shared__ __hip_bfloat16 As[128 * 32];
  __shared__ __hip_bfloat16 Bs[128 * 32];
  const int tid = threadIdx.x, lane = tid & 63, wid = tid >> 6;
  const int wr = wid >> 1, wc = wid & 1;
  const int cB = lane & 15, koff = (lane >> 4) * 8;
  const int rS0 = wid * 32 + (lane >> 2);
  const int rS1 = rS0 + 16;
  const int cby = (lane & 3) * 16;
  f32x4 acc[4][4] = {};
  for (int k0 = 0; k0 < 384; k0 += 32) {
    __syncthreads();
    gload16((const char*)(A + (size_t)(m0 + rS0) * 384 + k0) + cby, As + wid * 1024);
    gload16((const char*)(A + (size_t)(m0 + rS1) * 384 + k0) + cby, As + wid * 1024 + 512);
    gload16((const char*)(BT + (size_t)(n0 + rS0) * 384 + k0) + cby, Bs + wid * 1024);
    gload16((const char*)(BT + (size_t)(n0 + rS1) * 384 + k0) + cby, Bs + wid * 1024 + 512);
    __syncthreads();
    bf16x8 af[4], bfr[4];
#pragma unroll
    for (int i = 0; i < 4; ++i)
      af[i] = *reinterpret_cast<const bf16x8*>(&As[(wr * 64 + i * 16 + cB) * 32 + koff]);
#pragma unroll
    for (int j = 0; j < 4; ++j)
      bfr[j] = *reinterpret_cast<const bf16x8*>(&Bs[(wc * 64 + j * 16 + cB) * 32 + koff]);
#pragma unroll
    for (int i = 0; i < 4; ++i)
#pragma unroll
      for (int j = 0; j < 4; ++j)
        acc[i][j] = __builtin_amdgcn_mfma_f32_16x16x32_bf16(af[i], bfr[j], acc[i][j], 0, 0, 0);
  }
  const int rg = lane >> 4;
#pragma unroll
  for (int i = 0; i < 4; ++i)
#pragma unroll
    for (int j = 0; j < 4; ++j) {
      int col = n0 + wc * 64 + j * 16 + cB;
#pragma unroll
      for (int r = 0; r < 4; ++r) {
        int row = m0 + wr * 64 + i * 16 + rg * 4 + r;
        int bb = row / 361;
        int n = row - bb * 361;
        float res = x[((size_t)bb * 384 + col) * 361 + n];
        out[(size_t)row * 384 + col] = acc[i][j][r] + res;
      }
    }
}

extern "C" void kernel_launch(void* const* d_in, const int* in_sizes, int n_in,
                              void* d_out, int out_size, void* d_ws, size_t ws_size,
                              hipStream_t stream) {
  const float* x    = (const float*)d_in[0];
  const float* qw   = (const float*)d_in[1];
  const float* kw   = (const float*)d_in[2];
  const float* vw   = (const float*)d_in[3];
  const float* ow   = (const float*)d_in[4];
  const float* nw   = (const float*)d_in[5];
  const float* cost = (const float*)d_in[6];
  const float* sint = (const float*)d_in[7];
  float* out = (float*)d_out;
  char* ws = (char*)d_ws;

  const size_t SZ_XN = (size_t)M_TOT * 384 * 2;  // 35,487,744
  __hip_bfloat16* xn    = (__hip_bfloat16*)(ws);
  __hip_bfloat16* qkv   = (__hip_bfloat16*)(ws + SZ_XN);
  __hip_bfloat16* wqkvt = (__hip_bfloat16*)(ws + SZ_XN * 4);
  __hip_bfloat16* owt   = (__hip_bfloat16*)(ws + SZ_XN * 4 + 1152 * 384 * 2);
  __hip_bfloat16* ao    = xn;  // xn dead after QKV GEMM; reuse for attn out

  prep_w_kernel<<<576, 256, 0, stream>>>(qw, kw, vw, ow, wqkvt, owt);
  rms_t_kernel<<<128 * 12, 256, 0, stream>>>(x, nw, xn);
  qkv_gemm_kernel<<<361 * 9, 256, 0, stream>>>(xn, wqkvt, qkv);
  {
    size_t tot = (size_t)2 * M_TOT * 192;
    int blocks = (int)((tot + 255) / 256);
    rope_kernel<<<blocks, 256, 0, stream>>>(qkv, cost, sint);
  }
  attn_kernel<<<128 * 12, 512, 0, stream>>>(qkv, qkv + (size_t)M_TOT * 384,
                                            qkv + (size_t)2 * M_TOT * 384, ao);
  out_gemm_kernel<<<361 * 3, 256, 0, stream>>>(ao, owt, x, out);
}

// Round 10
// 445.453 us; speedup vs baseline: 1.1452x; 1.0494x over previous
//
#include <hip/hip_runtime.h>
#include <hip/hip_bf16.h>

typedef float f32x4 __attribute__((ext_vector_type(4)));
typedef __bf16 bf16x8 __attribute__((ext_vector_type(8)));

#define NPOS 361
#define NBATCH 128
#define M_TOT (NBATCH * NPOS)   // 46208

__device__ inline void gload16(const void* g, void* l) {
  __builtin_amdgcn_global_load_lds(
      (const __attribute__((address_space(1))) void*)g,
      (__attribute__((address_space(3))) void*)l, 16, 0, 0);
}

// rope on 8 consecutive head-dims starting at even offset; cp/sp point at cos/sin[n*32+d0]
__device__ inline bf16x8 rope8(bf16x8 in, const float* __restrict__ cp,
                               const float* __restrict__ sp) {
  bf16x8 out;
#pragma unroll
  for (int j = 0; j < 8; j += 2) {
    float x0 = (float)in[j], x1 = (float)in[j + 1];
    out[j]     = (__bf16)(x0 * cp[j] - x1 * sp[j]);
    out[j + 1] = (__bf16)(x1 * cp[j + 1] + x0 * sp[j + 1]);
  }
  return out;
}

// ---------------- kernel 0: LDS-tiled transpose of weights -> (N x K) bf16 ---
__global__ __launch_bounds__(256) void prep_w_kernel(
    const float* __restrict__ qw, const float* __restrict__ kw,
    const float* __restrict__ vw, const float* __restrict__ ow,
    __hip_bfloat16* __restrict__ wqkvt, __hip_bfloat16* __restrict__ owt) {
  int bid = blockIdx.x;                 // 4 * 144
  int si = bid / 144, t = bid % 144;
  int tr = (t / 12) * 32, tc = (t % 12) * 32;
  const float* src = si == 0 ? qw : si == 1 ? kw : si == 2 ? vw : ow;
  __hip_bfloat16* dst = si < 3 ? wqkvt + si * 147456 : owt;
  __shared__ float tile[32][33];
  int c = threadIdx.x & 31, r0 = threadIdx.x >> 5;
#pragma unroll
  for (int i = 0; i < 4; ++i) {
    int r = r0 + i * 8;
    tile[r][c] = src[(size_t)(tr + r) * 384 + tc + c];  // coalesced read
  }
  __syncthreads();
#pragma unroll
  for (int i = 0; i < 4; ++i) {
    int r = r0 + i * 8;
    dst[(size_t)(tc + r) * 384 + tr + c] = __float2bfloat16(tile[c][r]);  // coalesced write
  }
}

// ---------------- kernel 1: transpose (B,C,N)->(B,N,C) + RMSNorm -> bf16 ----
__global__ __launch_bounds__(256) void rms_t_kernel(
    const float* __restrict__ x, const float* __restrict__ nw,
    __hip_bfloat16* __restrict__ xn) {
  int b = blockIdx.x / 12, nt = blockIdx.x % 12;
  int n0 = nt * 32;
  __shared__ float xt[32 * 388];  // row len 388: 16B-aligned rows
  int tid = threadIdx.x;
  const float* xb = x + (size_t)b * (384 * 361);
  for (int idx = tid; idx < 384 * 32; idx += 256) {
    int j = idx & 31, c = idx >> 5;
    int n = n0 + j;
    xt[j * 388 + c] = (n < 361) ? xb[c * 361 + n] : 0.f;  // coalesced in n
  }
  __syncthreads();
  int lane = tid & 63, wid = tid >> 6;
  for (int j = wid; j < 32; j += 4) {
    int n = n0 + j;
    if (n >= 361) break;
    const float* row = &xt[j * 388];
    f32x4 v4 = *(const f32x4*)&row[lane * 4];         // c = 4*lane .. +3
    float va = row[256 + 2 * lane], vb2 = row[256 + 2 * lane + 1];
    float ss = v4[0] * v4[0] + v4[1] * v4[1] + v4[2] * v4[2] + v4[3] * v4[3] +
               va * va + vb2 * vb2;
#pragma unroll
    for (int off = 1; off < 64; off <<= 1) ss += __shfl_xor(ss, off);
    float inv = rsqrtf(ss * (1.f / 384.f) + 1e-6f);
    f32x4 w4 = *(const f32x4*)&nw[lane * 4];
    float wa = nw[256 + 2 * lane], wb = nw[256 + 2 * lane + 1];
    size_t rowo = ((size_t)b * 361 + n) * 384;
    __hip_bfloat162 p0 = __float22bfloat162_rn({v4[0] * inv * w4[0], v4[1] * inv * w4[1]});
    __hip_bfloat162 p1 = __float22bfloat162_rn({v4[2] * inv * w4[2], v4[3] * inv * w4[3]});
    __hip_bfloat162 p2 = __float22bfloat162_rn({va * inv * wa, vb2 * inv * wb});
    *(__hip_bfloat162*)&xn[rowo + lane * 4] = p0;
    *(__hip_bfloat162*)&xn[rowo + lane * 4 + 2] = p1;
    *(__hip_bfloat162*)&xn[rowo + 256 + 2 * lane] = p2;
  }
}

// ---------------- kernel 2: QKV GEMM, m97-style global_load_lds staging -----
__global__ __launch_bounds__(256) void qkv_gemm_kernel(
    const __hip_bfloat16* __restrict__ A, const __hip_bfloat16* __restrict__ BT,
    __hip_bfloat16* __restrict__ qkv) {
  const int nwg = 361 * 9;
  int orig = blockIdx.x;
  int xcd = orig & 7, loc = orig >> 3;
  const int q8 = nwg >> 3, r8 = nwg & 7;  // 406, 1 — bijective XCD swizzle (m204)
  int wgid = (xcd < r8 ? xcd * (q8 + 1) : r8 * (q8 + 1) + (xcd - r8) * q8) + loc;
  const int mt = wgid / 9, nt = wgid % 9;
  const int m0 = mt * 128, n0 = nt * 128;
  __shared__ __hip_bfloat16 As[128 * 32];  // linear: required by global_load_lds
  __shared__ __hip_bfloat16 Bs[128 * 32];
  const int tid = threadIdx.x, lane = tid & 63, wid = tid >> 6;
  const int wr = wid >> 1, wc = wid & 1;
  const int cB = lane & 15, koff = (lane >> 4) * 8;
  const int rS0 = wid * 32 + (lane >> 2);       // staging row, issue 0
  const int rS1 = rS0 + 16;                     // issue 1
  const int cby = (lane & 3) * 16;              // byte offset within 64B LDS row
  f32x4 acc[4][4] = {};
  for (int k0 = 0; k0 < 384; k0 += 32) {
    __syncthreads();
    gload16((const char*)(A + (size_t)(m0 + rS0) * 384 + k0) + cby, As + wid * 1024);
    gload16((const char*)(A + (size_t)(m0 + rS1) * 384 + k0) + cby, As + wid * 1024 + 512);
    gload16((const char*)(BT + (size_t)(n0 + rS0) * 384 + k0) + cby, Bs + wid * 1024);
    gload16((const char*)(BT + (size_t)(n0 + rS1) * 384 + k0) + cby, Bs + wid * 1024 + 512);
    __syncthreads();  // compiler drains vmcnt before barrier
    bf16x8 af[4], bfr[4];
#pragma unroll
    for (int i = 0; i < 4; ++i)
      af[i] = *reinterpret_cast<const bf16x8*>(&As[(wr * 64 + i * 16 + cB) * 32 + koff]);
#pragma unroll
    for (int j = 0; j < 4; ++j)
      bfr[j] = *reinterpret_cast<const bf16x8*>(&Bs[(wc * 64 + j * 16 + cB) * 32 + koff]);
#pragma unroll
    for (int i = 0; i < 4; ++i)
#pragma unroll
      for (int j = 0; j < 4; ++j)
        acc[i][j] = __builtin_amdgcn_mfma_f32_16x16x32_bf16(af[i], bfr[j], acc[i][j], 0, 0, 0);
  }
  const int rg = lane >> 4;
  const int sel = n0 / 384;
  __hip_bfloat16* dst = qkv + (size_t)sel * M_TOT * 384;
#pragma unroll
  for (int i = 0; i < 4; ++i)
#pragma unroll
    for (int j = 0; j < 4; ++j) {
      int cc = n0 - sel * 384 + wc * 64 + j * 16 + cB;
#pragma unroll
      for (int r = 0; r < 4; ++r) {
        int row = m0 + wr * 64 + i * 16 + rg * 4 + r;
        dst[(size_t)row * 384 + cc] = __float2bfloat16(acc[i][j][r]);
      }
    }
}

// ---------------- kernel 4: attention, round-2 structure + fused RoPE ONLY --
__global__ __launch_bounds__(512) void attn_kernel(
    const __hip_bfloat16* __restrict__ q, const __hip_bfloat16* __restrict__ k,
    const __hip_bfloat16* __restrict__ v, __hip_bfloat16* __restrict__ o,
    const float* __restrict__ cost, const float* __restrict__ sint) {
  const int b = blockIdx.x / 12, h = blockIdx.x % 12;
  __shared__ __hip_bfloat16 Ks[368][40];   // roped K rows, 2-way max on b-frag reads
  __shared__ __hip_bfloat16 VT[32][392];   // V transposed; cols >=361 zeroed
  __shared__ __hip_bfloat16 Pb[8][16][40]; // per-wave P chunk (16x32)
  const int tid = threadIdx.x, lane = tid & 63, wid = tid >> 6;
  const size_t base = ((size_t)b * 361) * 384 + (size_t)h * 32;
  const __hip_bfloat16* qb = q + base;
  const __hip_bfloat16* kb = k + base;
  const __hip_bfloat16* vb = v + base;
  // K stage with fused RoPE (delta under test this round)
  for (int idx = tid; idx < 368 * 4; idx += 512) {
    int m = idx >> 2, c8 = (idx & 3) * 8;
    int mc = m < 361 ? m : 360;  // rows >=361 masked in softmax; keep finite
    bf16x8 kv = *reinterpret_cast<const bf16x8*>(&kb[(size_t)mc * 384 + c8]);
    *reinterpret_cast<bf16x8*>(&Ks[m][c8]) =
        rope8(kv, &cost[mc * 32 + c8], &sint[mc * 32 + c8]);
  }
  for (int idx = tid; idx < 384 * 32; idx += 512) {
    int m = idx >> 5, d = idx & 31;
    float val = (m < 361) ? __bfloat162float(vb[(size_t)m * 384 + d]) : 0.f;
    VT[d][m] = __float2bfloat16(val);
  }
  __syncthreads();
  const int cB = lane & 15, rg = lane >> 4, koff = rg * 8;
  const float scale = 0.17677669529663688f;  // 1/sqrt(32)
  for (int rt = wid; rt < 23; rt += 8) {
    int qrow = rt * 16 + cB;
    if (qrow > 360) qrow = 360;  // clamped rows produce unstored garbage only
    bf16x8 qv = *reinterpret_cast<const bf16x8*>(&qb[(size_t)qrow * 384 + koff]);
    bf16x8 af = rope8(qv, &cost[qrow * 32 + koff], &sint[qrow * 32 + koff]);
    f32x4 S[23];
#pragma unroll
    for (int mt = 0; mt < 23; ++mt) {
      bf16x8 bfr = *reinterpret_cast<const bf16x8*>(&Ks[mt * 16 + cB][koff]);
      f32x4 z = {};
      S[mt] = __builtin_amdgcn_mfma_f32_16x16x32_bf16(af, bfr, z, 0, 0, 0);
    }
    float mx[4] = {-1e30f, -1e30f, -1e30f, -1e30f};
#pragma unroll
    for (int mt = 0; mt < 23; ++mt)
#pragma unroll
      for (int r = 0; r < 4; ++r) {
        float s = S[mt][r] * scale;
        if (mt == 22 && cB >= 9) s = -1e30f;  // cols 361..367 masked
        S[mt][r] = s;
        mx[r] = fmaxf(mx[r], s);
      }
#pragma unroll
    for (int off = 1; off < 16; off <<= 1)
#pragma unroll
      for (int r = 0; r < 4; ++r) mx[r] = fmaxf(mx[r], __shfl_xor(mx[r], off));
    float sum[4] = {0.f, 0.f, 0.f, 0.f};
#pragma unroll
    for (int mt = 0; mt < 23; ++mt)
#pragma unroll
      for (int r = 0; r < 4; ++r) {
        float pv = __expf(S[mt][r] - mx[r]);
        S[mt][r] = pv;
        sum[r] += pv;
      }
#pragma unroll
    for (int off = 1; off < 16; off <<= 1)
#pragma unroll
      for (int r = 0; r < 4; ++r) sum[r] += __shfl_xor(sum[r], off);
    f32x4 O0 = {}, O1 = {};
#pragma unroll
    for (int km = 0; km < 12; ++km) {
#pragma unroll
      for (int t2 = 0; t2 < 2; ++t2) {
        int mt = km * 2 + t2;
#pragma unroll
        for (int r = 0; r < 4; ++r) {
          float pv = (mt < 23) ? S[mt][r] : 0.f;
          Pb[wid][rg * 4 + r][t2 * 16 + cB] = __float2bfloat16(pv);
        }
      }
      // same-wave DS ops are ordered; compiler inserts lgkmcnt for the reads
      bf16x8 pa = *reinterpret_cast<const bf16x8*>(&Pb[wid][cB][koff]);
      bf16x8 bv0 = *reinterpret_cast<const bf16x8*>(&VT[cB][km * 32 + koff]);
      bf16x8 bv1 = *reinterpret_cast<const bf16x8*>(&VT[16 + cB][km * 32 + koff]);
      O0 = __builtin_amdgcn_mfma_f32_16x16x32_bf16(pa, bv0, O0, 0, 0, 0);
      O1 = __builtin_amdgcn_mfma_f32_16x16x32_bf16(pa, bv1, O1, 0, 0, 0);
    }
#pragma unroll
    for (int r = 0; r < 4; ++r) {
      int n = rt * 16 + rg * 4 + r;
      if (n < 361) {
        float is = 1.f / sum[r];
        o[base + (size_t)n * 384 + cB] = __float2bfloat16(O0[r] * is);
        o[base + (size_t)n * 384 + 16 + cB] = __float2bfloat16(O1[r] * is);
      }
    }
  }
}

// ---------------- kernel 5: out-proj GEMM + residual (f32 out) --------------
__global__ __launch_bounds__(256) void out_gemm_kernel(
    const __hip_bfloat16* __restrict__ A, const __hip_bfloat16* __restrict__ BT,
    const float* __restrict__ x, float* __restrict__ out) {
  const int nwg = 361 * 3;
  int orig = blockIdx.x;
  int xcd = orig & 7, loc = orig >> 3;
  const int q8 = nwg >> 3, r8 = nwg & 7;  // 135, 3
  int wgid = (xcd < r8 ? xcd * (q8 + 1) : r8 * (q8 + 1) + (xcd - r8) * q8) + loc;
  const int mt = wgid / 3, nt = wgid % 3;
  const int m0 = mt * 128, n0 = nt * 128;
  __shared__ __hip_bfloat16 As[128 * 32];
  __shared__ __hip_bfloat16 Bs[128 * 32];
  const int tid = threadIdx.x, lane = tid & 63, wid = tid >> 6;
  const int wr = wid >> 1, wc = wid & 1;
  const int cB = lane & 15, koff = (lane >> 4) * 8;
  const int rS0 = wid * 32 + (lane >> 2);
  const int rS1 = rS0 + 16;
  const int cby = (lane & 3) * 16;
  f32x4 acc[4][4] = {};
  for (int k0 = 0; k0 < 384; k0 += 32) {
    __syncthreads();
    gload16((const char*)(A + (size_t)(m0 + rS0) * 384 + k0) + cby, As + wid * 1024);
    gload16((const char*)(A + (size_t)(m0 + rS1) * 384 + k0) + cby, As + wid * 1024 + 512);
    gload16((const char*)(BT + (size_t)(n0 + rS0) * 384 + k0) + cby, Bs + wid * 1024);
    gload16((const char*)(BT + (size_t)(n0 + rS1) * 384 + k0) + cby, Bs + wid * 1024 + 512);
    __syncthreads();
    bf16x8 af[4], bfr[4];
#pragma unroll
    for (int i = 0; i < 4; ++i)
      af[i] = *reinterpret_cast<const bf16x8*>(&As[(wr * 64 + i * 16 + cB) * 32 + koff]);
#pragma unroll
    for (int j = 0; j < 4; ++j)
      bfr[j] = *reinterpret_cast<const bf16x8*>(&Bs[(wc * 64 + j * 16 + cB) * 32 + koff]);
#pragma unroll
    for (int i = 0; i < 4; ++i)
#pragma unroll
      for (int j = 0; j < 4; ++j)
        acc[i][j] = __builtin_amdgcn_mfma_f32_16x16x32_bf16(af[i], bfr[j], acc[i][j], 0, 0, 0);
  }
  const int rg = lane >> 4;
#pragma unroll
  for (int i = 0; i < 4; ++i)
#pragma unroll
    for (int j = 0; j < 4; ++j) {
      int col = n0 + wc * 64 + j * 16 + cB;
#pragma unroll
      for (int r = 0; r < 4; ++r) {
        int row = m0 + wr * 64 + i * 16 + rg * 4 + r;
        int bb = row / 361;
        int n = row - bb * 361;
        float res = x[((size_t)bb * 384 + col) * 361 + n];
        out[(size_t)row * 384 + col] = acc[i][j][r] + res;
      }
    }
}

extern "C" void kernel_launch(void* const* d_in, const int* in_sizes, int n_in,
                              void* d_out, int out_size, void* d_ws, size_t ws_size,
                              hipStream_t stream) {
  const float* x    = (const float*)d_in[0];
  const float* qw   = (const float*)d_in[1];
  const float* kw   = (const float*)d_in[2];
  const float* vw   = (const float*)d_in[3];
  const float* ow   = (const float*)d_in[4];
  const float* nw   = (const float*)d_in[5];
  const float* cost = (const float*)d_in[6];
  const float* sint = (const float*)d_in[7];
  float* out = (float*)d_out;
  char* ws = (char*)d_ws;

  const size_t SZ_XN = (size_t)M_TOT * 384 * 2;  // 35,487,744
  __hip_bfloat16* xn    = (__hip_bfloat16*)(ws);
  __hip_bfloat16* qkv   = (__hip_bfloat16*)(ws + SZ_XN);
  __hip_bfloat16* wqkvt = (__hip_bfloat16*)(ws + SZ_XN * 4);
  __hip_bfloat16* owt   = (__hip_bfloat16*)(ws + SZ_XN * 4 + 1152 * 384 * 2);
  __hip_bfloat16* ao    = xn;  // xn dead after QKV GEMM; reuse for attn out

  prep_w_kernel<<<576, 256, 0, stream>>>(qw, kw, vw, ow, wqkvt, owt);
  rms_t_kernel<<<128 * 12, 256, 0, stream>>>(x, nw, xn);
  qkv_gemm_kernel<<<361 * 9, 256, 0, stream>>>(xn, wqkvt, qkv);
  attn_kernel<<<128 * 12, 512, 0, stream>>>(qkv, qkv + (size_t)M_TOT * 384,
                                            qkv + (size_t)2 * M_TOT * 384, ao,
                                            cost, sint);
  out_gemm_kernel<<<361 * 3, 256, 0, stream>>>(ao, owt, x, out);
}